// Round 8
// baseline (308.087 us; speedup 1.0000x reference)
//
#include <hip/hip_runtime.h>
#include <hip/hip_bf16.h>
#include <math.h>

// ---------------------------------------------------------------------------
// BNAF flow (DIM=64, HID=32, B=1024).  R23: R19 bodies (291us baseline) +
// (a) prep_mega regrouped 4 rows/256-thr block (grid 12480->3120);
// (b) tail_trans(f)+gemm0(f+1) fused REUSE-PRESERVING: grid (8,64); every
// block redundantly recomputes x_next for its 16 rows from out2p (L2-hot),
// keeps them in LDS, runs the unchanged 16-row gemm0 phase; bx==0 blocks
// also do ldj + global x_next writes. 11 dispatches.
// ---------------------------------------------------------------------------

#define DIMN 64
#define BATCH 1024
#define HIDF 2048   // DIM*HID
#define SPLITK 4
#define NT2 32      // out2 partial count (= HIDF/64 n-tiles)

typedef __attribute__((ext_vector_type(8))) short short8;
typedef __attribute__((ext_vector_type(4))) float floatx4;
typedef __hip_bfloat16 bf16;

__device__ __forceinline__ float softplusf_(float t) {
    return fmaxf(t, 0.f) + log1pf(__expf(-fabsf(t)));
}

__device__ __forceinline__ float bf2f(short v) {
    union { unsigned u; float f; } x;
    x.u = ((unsigned)(unsigned short)v) << 16;
    return x.f;
}

__device__ __forceinline__ void gl_lds16(const void* g, void* l) {
    __builtin_amdgcn_global_load_lds(
        (const __attribute__((address_space(1))) unsigned int*)g,
        (__attribute__((address_space(3))) unsigned int*)l, 16, 0, 0);
}

// tanh + sech^2 from ONE exp.
__device__ __forceinline__ void tanh_sech2_(float p, float& th, float& s2) {
    float t = __expf(-2.f * fabsf(p));
    float opt = 1.f + t;
    float inv = 1.f / opt;
    th = copysignf((1.f - t) * inv, p);
    s2 = 4.f * t * inv * inv;
}

// ---------------------------------------------------------------------------
// prep row worker (R16 form): one wave per output row r of W (out_f x INF).
// ---------------------------------------------------------------------------
template<int INF>
__device__ __forceinline__ void prep_row(
    const float* __restrict__ W, const float* __restrict__ dw,
    void* __restrict__ wn_out, float* __restrict__ eg,
    int r, int lane, int out_f, int ob, int ib, int transpose, int bf16out)
{
    constexpr int NI = INF / 64;
    int d = r / ob;
    int c0 = d * ib;
    int c1 = c0 + ib;
    const float* Wr = W + (size_t)r * INF;

    float vv[NI];
    float ss = 0.f;
#pragma unroll
    for (int i = 0; i < NI; ++i) {
        int c = lane + i * 64;
        float wraw = Wr[c];
        float wv = (c < c0) ? wraw : ((c < c1) ? __expf(wraw) : 0.f);
        vv[i] = wv;
        ss += wv * wv;
    }
    for (int off = 32; off > 0; off >>= 1) ss += __shfl_xor(ss, off, 64);

    float dwr = dw[r];
    float scale = __expf(dwr) / sqrtf(ss);
    float logt = dwr - 0.5f * __logf(ss);

#pragma unroll
    for (int i = 0; i < NI; ++i) {
        int c = lane + i * 64;
        float val = scale * vv[i];
        if (bf16out) {
            ((bf16*)wn_out)[(size_t)r * INF + c] = __float2bfloat16(val);
        } else if (transpose) {
            ((float*)wn_out)[(size_t)c * out_f + r] = val;
        } else {
            ((float*)wn_out)[(size_t)r * INF + c] = val;
        }
    }
    if (lane < ib) eg[(size_t)r * ib + lane] = __expf(logt + Wr[c0 + lane]);
}

struct PrepIn { const float *W0, *dw0, *W1, *dw1, *W2, *dw2; };

// R23: 4 rows per 256-thread block (one row per wave). grid 3 * 1040 = 3120.
__global__ __launch_bounds__(256) void prep_mega(
    PrepIn p0, PrepIn p1, PrepIn p2,
    float* __restrict__ wn0T_all, float* __restrict__ eg0_all,
    bf16* __restrict__ wn1_all, float* __restrict__ e1_all,
    bf16* __restrict__ wn2b_all, float* __restrict__ e2_all)
{
    int blk = blockIdx.x;
    int wave = threadIdx.x >> 6;
    int lane = threadIdx.x & 63;
    int f = blk / 1040;
    int rem = blk - f * 1040;
    int rr = rem * 4 + wave;             // 0..4159 within flow
    PrepIn P = (f == 0) ? p0 : ((f == 1) ? p1 : p2);

    float* wn0T = wn0T_all + (size_t)f * DIMN * HIDF;
    float* eg0  = eg0_all  + (size_t)f * HIDF;
    bf16* wn1   = wn1_all + (size_t)f * HIDF * HIDF;
    float* e1   = e1_all   + (size_t)f * HIDF * 32;
    bf16* wn2b  = wn2b_all + (size_t)f * DIMN * HIDF;
    float* e2   = e2_all   + (size_t)f * DIMN * 32;

    if (rr < HIDF) {
        prep_row<DIMN>(P.W0, P.dw0, wn0T, eg0, rr, lane, HIDF, 32, 1, 1, 0);
    } else if (rr < 2 * HIDF) {
        prep_row<HIDF>(P.W1, P.dw1, wn1, e1, rr - HIDF, lane, HIDF, 32, 32, 0, 1);
    } else {
        prep_row<HIDF>(P.W2, P.dw2, wn2b, e2, rr - 2 * HIDF, lane, DIMN, 1, 32, 0, 1);
    }
}

// ---------------------------------------------------------------------------
// gemm0_act (flow 0 only): pre0 = x @ wn0T + b0 ; h0 = tanh bf16;
// g0e = eg0 * sech^2 (bf16). grid (8, 64), 256 threads.
// ---------------------------------------------------------------------------
__global__ __launch_bounds__(256) void gemm0_act(
    const float* __restrict__ xin, const float* __restrict__ wn0T,
    const float* __restrict__ bias, const float* __restrict__ eg0,
    bf16* __restrict__ h0, bf16* __restrict__ g0e)
{
    __shared__ float xs[16][DIMN];
    int b0 = blockIdx.y * 16;
    {
        const float4* src = (const float4*)(xin + (size_t)b0 * DIMN);
        ((float4*)xs)[threadIdx.x] = src[threadIdx.x];
    }
    __syncthreads();
    int n = blockIdx.x * 256 + threadIdx.x;

    float acc[16];
#pragma unroll
    for (int j = 0; j < 16; ++j) acc[j] = 0.f;

#pragma unroll 4
    for (int c4 = 0; c4 < 16; ++c4) {
        int c = c4 * 4;
        float w0 = wn0T[(size_t)(c + 0) * HIDF + n];
        float w1 = wn0T[(size_t)(c + 1) * HIDF + n];
        float w2 = wn0T[(size_t)(c + 2) * HIDF + n];
        float w3 = wn0T[(size_t)(c + 3) * HIDF + n];
#pragma unroll
        for (int j = 0; j < 16; ++j) {
            float4 x4 = *(const float4*)&xs[j][c];
            acc[j] = fmaf(x4.x, w0, acc[j]);
            acc[j] = fmaf(x4.y, w1, acc[j]);
            acc[j] = fmaf(x4.z, w2, acc[j]);
            acc[j] = fmaf(x4.w, w3, acc[j]);
        }
    }
    float bv = bias[n], egv = eg0[n];
#pragma unroll
    for (int j = 0; j < 16; ++j) {
        float p = acc[j] + bv;
        float th, s2;
        tanh_sech2_(p, th, s2);
        size_t idx = (size_t)(b0 + j) * HIDF + n;
        h0[idx] = __float2bfloat16(th);
        g0e[idx] = __float2bfloat16(egv * s2);
    }
}

// ---------------------------------------------------------------------------
// gemm1_part (R19 form): 128x128 tile, LPT live triangular schedule,
// single-buffered staging. grid 320.
// ---------------------------------------------------------------------------
__constant__ unsigned char G1_JN[40] = {
    3,4,5,6,7,7,8,8,9,9,10,10,11,11,11,12,12,12,13,13,13,14,14,14,
    15,15,15,15, 2,6,10,14, 1,5,9,13, 0,4,8,12 };
__constant__ unsigned char G1_KZ[40] = {
    0,0,0,0,0,1,0,1,0,1, 0, 1, 0, 1, 2, 0, 1, 2, 0, 1, 2, 0, 1, 2,
     0, 1, 2, 3, 0,1, 2, 3, 0,1,2,3, 0,1,2,3 };

#define G1BK 64
__global__ __launch_bounds__(256) void gemm1_part(
    const bf16* __restrict__ A, const bf16* __restrict__ B,
    bf16* __restrict__ part)
{
    const int K = HIDF, N = HIDF;
    int pr = blockIdx.x >> 3;
    int my = blockIdx.x & 7;
    int jn = G1_JN[pr];
    int kz = G1_KZ[pr];
    int kbase = kz * (K / SPLITK);
    int kend = (jn + 1) * 128 - kbase;
    if (kend > K / SPLITK) kend = K / SPLITK;

    __shared__ short As[128 * 64];
    __shared__ short Bs[128 * 64];
    int tid = threadIdx.x;
    int lane = tid & 63;
    int wave = tid >> 6;
    int n0 = jn * 128;
    int m0 = my * 128;
    int wr = wave >> 1;
    int wc = wave & 1;
    int rf = lane & 15;
    int q = lane >> 4;

    const char* agp[4];
    const char* bgp[4];
    char* alds[4];
    char* blds[4];
#pragma unroll
    for (int s = 0; s < 4; ++s) {
        int c = tid + s * 256;
        int row = c >> 3;
        int kc = (c & 7) ^ (row & 7);
        agp[s] = (const char*)A + ((size_t)(m0 + row) * K + kbase) * 2 + kc * 16;
        bgp[s] = (const char*)B + ((size_t)(n0 + row) * K + kbase) * 2 + kc * 16;
        alds[s] = (char*)As + c * 16;
        blds[s] = (char*)Bs + c * 16;
    }

    floatx4 acc[4][4];
#pragma unroll
    for (int i = 0; i < 4; ++i)
#pragma unroll
        for (int j = 0; j < 4; ++j) acc[i][j] = (floatx4){0.f, 0.f, 0.f, 0.f};

    int rowA0 = wr * 64 + rf;
    int rowB0 = wc * 64 + rf;

    for (int k0 = 0; k0 < kend; k0 += G1BK) {
        size_t kb = (size_t)k0 * 2;
        __syncthreads();
#pragma unroll
        for (int s = 0; s < 4; ++s) {
            gl_lds16(agp[s] + kb, alds[s]);
            gl_lds16(bgp[s] + kb, blds[s]);
        }
        __syncthreads();

#pragma unroll
        for (int s = 0; s < 2; ++s) {
            short8 af[4], bfv[4];
#pragma unroll
            for (int i = 0; i < 4; ++i) {
                int row = rowA0 + i * 16;
                af[i] = *(const short8*)&As[row * 64 + (((s * 4 + q) ^ (row & 7)) * 8)];
            }
#pragma unroll
            for (int j = 0; j < 4; ++j) {
                int row = rowB0 + j * 16;
                bfv[j] = *(const short8*)&Bs[row * 64 + (((s * 4 + q) ^ (row & 7)) * 8)];
            }
#pragma unroll
            for (int i = 0; i < 4; ++i)
#pragma unroll
                for (int j = 0; j < 4; ++j)
                    acc[i][j] = __builtin_amdgcn_mfma_f32_16x16x32_bf16(af[i], bfv[j], acc[i][j], 0, 0, 0);
        }
    }

    bf16* pk = part + (size_t)kz * BATCH * HIDF;
    int col = lane & 15;
    int rq = (lane >> 4) * 4;
#pragma unroll
    for (int i = 0; i < 4; ++i) {
#pragma unroll
        for (int j = 0; j < 4; ++j) {
            int n = n0 + wc * 64 + j * 16 + col;
#pragma unroll
            for (int r = 0; r < 4; ++r) {
                int m = m0 + wr * 64 + i * 16 + rq + r;
                pk[(size_t)m * N + n] = __float2bfloat16(acc[i][j][r]);
            }
        }
    }
}

// ---------------------------------------------------------------------------
// act_grad_gemm2 (R19 branch-free form).
// ---------------------------------------------------------------------------
__global__ __launch_bounds__(256) void act_grad_gemm2(
    const bf16* __restrict__ part, const float* __restrict__ bias,
    const float* __restrict__ e1, const bf16* __restrict__ g0e,
    const bf16* __restrict__ wn2b,
    bf16* __restrict__ grad1e, float* __restrict__ out2p)
{
    __shared__ char smem[17408 + 8704 + 8192];
    float* g0s = (float*)smem;
    short* h1s = (short*)(smem + 17408);
    short* Bs2 = (short*)(smem + 17408 + 8704);

    int tid = threadIdx.x;
    int lane = tid & 63;
    int wave = tid >> 6;
    int bx = blockIdx.x;
    int n0 = bx * 64;
    int b0 = blockIdx.y * 64;
    int np = (bx >> 3) + 1;

    {
        int c0c = tid, c1c = tid + 256;
        int r0 = c0c >> 3, k0c = (c0c & 7) ^ (r0 & 7);
        int r1 = c1c >> 3, k1c = (c1c & 7) ^ (r1 & 7);
        gl_lds16((const char*)wn2b + ((size_t)r0 * HIDF + n0) * 2 + k0c * 16,
                 (char*)Bs2 + c0c * 16);
        gl_lds16((const char*)wn2b + ((size_t)r1 * HIDF + n0) * 2 + k1c * 16,
                 (char*)Bs2 + c1c * 16);
    }

    for (int s = tid; s < 512; s += 256) {
        int row = s >> 3, c8 = s & 7;
        short8 v = *(const short8*)((const short*)g0e +
                                    (size_t)(b0 + row) * HIDF + n0 + c8 * 8);
        float4 lo = { bf2f(v[0]), bf2f(v[1]), bf2f(v[2]), bf2f(v[3]) };
        float4 hi = { bf2f(v[4]), bf2f(v[5]), bf2f(v[6]), bf2f(v[7]) };
        *(float4*)&g0s[row * 68 + c8 * 8] = lo;
        *(float4*)&g0s[row * 68 + c8 * 8 + 4] = hi;
    }

    int g = tid >> 6;
    int nl = tid & 63;
    int n = n0 + nl;

    float4 er[8];
    const float4* e1r = (const float4*)(e1 + (size_t)n * 32);
#pragma unroll
    for (int qq = 0; qq < 8; ++qq) er[qq] = e1r[qq];

    float bv = bias[n];
    int kb2 = nl & 32;
    const bf16* pp0 = part;
    const bf16* pp1 = (np > 1) ? part + (size_t)1 * BATCH * HIDF : part;
    const bf16* pp2 = (np > 2) ? part + (size_t)2 * BATCH * HIDF : part;
    const bf16* pp3 = (np > 3) ? part + (size_t)3 * BATCH * HIDF : part;
    float m1 = (np > 1) ? 1.f : 0.f;
    float m2 = (np > 2) ? 1.f : 0.f;
    float m3 = (np > 3) ? 1.f : 0.f;

    __syncthreads();

#pragma unroll
    for (int t = 0; t < 16; ++t) {
        int bl = g * 16 + t;
        int b = b0 + bl;
        size_t idx = (size_t)b * HIDF + n;
        float l0 = __bfloat162float(pp0[idx]);
        float l1 = __bfloat162float(pp1[idx]);
        float l2 = __bfloat162float(pp2[idx]);
        float l3 = __bfloat162float(pp3[idx]);
        float pre = bv + l0;
        pre = fmaf(m1, l1, pre);
        pre = fmaf(m2, l2, pre);
        pre = fmaf(m3, l3, pre);
        float th, s2;
        tanh_sech2_(pre, th, s2);
        const float* g0row = &g0s[bl * 68 + kb2];
        float dot = 0.f;
#pragma unroll
        for (int qq = 0; qq < 8; ++qq) {
            float4 gv = *(const float4*)&g0row[qq * 4];
            dot = fmaf(gv.x, er[qq].x, dot);
            dot = fmaf(gv.y, er[qq].y, dot);
            dot = fmaf(gv.z, er[qq].z, dot);
            dot = fmaf(gv.w, er[qq].w, dot);
        }
        bf16 thb = __float2bfloat16(th);
        h1s[bl * 68 + nl] = *(const short*)&thb;
        grad1e[idx] = __float2bfloat16(dot * s2);
    }
    __syncthreads();

    int rf = lane & 15;
    int q = lane >> 4;
    floatx4 acc2[4];
#pragma unroll
    for (int j = 0; j < 4; ++j) acc2[j] = (floatx4){0.f, 0.f, 0.f, 0.f};

#pragma unroll
    for (int s = 0; s < 2; ++s) {
        int rowa = wave * 16 + rf;
        short8 af = *(const short8*)&h1s[rowa * 68 + s * 32 + q * 8];
#pragma unroll
        for (int j = 0; j < 4; ++j) {
            int rowb = j * 16 + rf;
            int cp = (s * 4 + q) ^ (rowb & 7);
            short8 bfv = *(const short8*)&Bs2[rowb * 64 + cp * 8];
            acc2[j] = __builtin_amdgcn_mfma_f32_16x16x32_bf16(af, bfv, acc2[j], 0, 0, 0);
        }
    }

    float* outk = out2p + (size_t)bx * BATCH * DIMN;
    int col = lane & 15;
    int rq = (lane >> 4) * 4;
#pragma unroll
    for (int j = 0; j < 4; ++j) {
#pragma unroll
        for (int r = 0; r < 4; ++r) {
            int m = b0 + wave * 16 + rq + r;
            outk[(size_t)m * DIMN + j * 16 + col] = acc2[j][r];
        }
    }
}

// ---------------------------------------------------------------------------
// tail_gemm0 v2: FUSED tail_trans(f) + gemm0(f+1), reuse-preserving.
// grid (8, 64) like standalone gemm0. Every block recomputes x_next for its
// 16 rows (redundant out2p o-sums, L2-hot) into LDS; bx==0 additionally
// does the ldj log-part and the global x_next/ldj writes. Phase 2 is the
// UNCHANGED gemm0 body (16-row weight reuse).
// ---------------------------------------------------------------------------
__global__ __launch_bounds__(256) void tail_gemm0(
    const float* __restrict__ out2p, const float* __restrict__ b2,
    const float* __restrict__ e2, const bf16* __restrict__ grad1e,
    const float* __restrict__ x_cur, const float* __restrict__ gate,
    float* __restrict__ x_next, float* __restrict__ ldj, int accum_ldj,
    const float* __restrict__ wn0T_n, const float* __restrict__ bias_n,
    const float* __restrict__ eg0_n,
    bf16* __restrict__ h0, bf16* __restrict__ g0e)
{
    __shared__ float xs[16][DIMN];
    int tid = threadIdx.x;
    int bx = blockIdx.x;       // n-chunk 0..7
    int b0 = blockIdx.y * 16;  // row group
    int n = tid & 63;
    int rowg = tid >> 6;       // 0..3 (wave id)

    float gt = gate[0];
    float sg = 1.f / (1.f + __expf(-gt));
    float bv2 = b2[n];

    // ---- phase 1: rebuild x_next rows 16 (4 per wave) ----
#pragma unroll
    for (int i = 0; i < 4; ++i) {
        int row = rowg * 4 + i;
        int b = b0 + row;
        float o = bv2;
#pragma unroll
        for (int p = 0; p < NT2; ++p)
            o += out2p[(size_t)p * BATCH * DIMN + (size_t)b * DIMN + n];
        float xo = sg * o + (1.f - sg) * x_cur[(size_t)b * DIMN + n];
        xs[row][63 - n] = xo;

        if (bx == 0) {
            x_next[(size_t)b * DIMN + (63 - n)] = xo;
            const short8* gr = (const short8*)((const short*)grad1e +
                                               (size_t)b * HIDF + n * 32);
            const float4* gc = (const float4*)(e2 + n * 32);
            float s = 0.f;
#pragma unroll
            for (int q = 0; q < 4; ++q) {
                short8 a8 = gr[q];
                float4 c0 = gc[2 * q], c1 = gc[2 * q + 1];
                s = fmaf(bf2f(a8[0]), c0.x, s);
                s = fmaf(bf2f(a8[1]), c0.y, s);
                s = fmaf(bf2f(a8[2]), c0.z, s);
                s = fmaf(bf2f(a8[3]), c0.w, s);
                s = fmaf(bf2f(a8[4]), c1.x, s);
                s = fmaf(bf2f(a8[5]), c1.y, s);
                s = fmaf(bf2f(a8[6]), c1.z, s);
                s = fmaf(bf2f(a8[7]), c1.w, s);
            }
            float gF = __logf(fmaxf(s, 1e-45f));
            float contrib = softplusf_(gF + gt) - softplusf_(gt);
            for (int off = 32; off > 0; off >>= 1)
                contrib += __shfl_xor(contrib, off, 64);
            if (n == 0) ldj[b] = accum_ldj ? (ldj[b] + contrib) : contrib;
        }
    }
    __syncthreads();

    // ---- phase 2: UNCHANGED gemm0 body (next flow) ----
    int nn = bx * 256 + tid;

    float acc[16];
#pragma unroll
    for (int j = 0; j < 16; ++j) acc[j] = 0.f;

#pragma unroll 4
    for (int c4 = 0; c4 < 16; ++c4) {
        int c = c4 * 4;
        float w0 = wn0T_n[(size_t)(c + 0) * HIDF + nn];
        float w1 = wn0T_n[(size_t)(c + 1) * HIDF + nn];
        float w2 = wn0T_n[(size_t)(c + 2) * HIDF + nn];
        float w3 = wn0T_n[(size_t)(c + 3) * HIDF + nn];
#pragma unroll
        for (int j = 0; j < 16; ++j) {
            float4 x4 = *(const float4*)&xs[j][c];
            acc[j] = fmaf(x4.x, w0, acc[j]);
            acc[j] = fmaf(x4.y, w1, acc[j]);
            acc[j] = fmaf(x4.z, w2, acc[j]);
            acc[j] = fmaf(x4.w, w3, acc[j]);
        }
    }
    float bvn = bias_n[nn], egv = eg0_n[nn];
#pragma unroll
    for (int j = 0; j < 16; ++j) {
        float p = acc[j] + bvn;
        float th, s2;
        tanh_sech2_(p, th, s2);
        size_t idx = (size_t)(b0 + j) * HIDF + nn;
        h0[idx] = __float2bfloat16(th);
        g0e[idx] = __float2bfloat16(egv * s2);
    }
}

// ---------------------------------------------------------------------------
// tail_final (flow 2): out[b] = ldj[b] + sum_n(gF - 0.5*o^2 - 0.5*log(2pi))
// ---------------------------------------------------------------------------
__global__ __launch_bounds__(256) void tail_final(
    const float* __restrict__ out2p, const float* __restrict__ b2,
    const float* __restrict__ e2, const bf16* __restrict__ grad1e,
    const float* __restrict__ ldj, float* __restrict__ out)
{
    int tid = threadIdx.x;
    int b = blockIdx.x * 4 + (tid >> 6);
    int n = tid & 63;

    float o = b2[n];
#pragma unroll
    for (int p = 0; p < NT2; ++p)
        o += out2p[(size_t)p * BATCH * DIMN + (size_t)b * DIMN + n];

    const short8* gr = (const short8*)((const short*)grad1e + (size_t)b * HIDF + n * 32);
    const float4* gc = (const float4*)(e2 + n * 32);
    float s = 0.f;
#pragma unroll
    for (int q = 0; q < 4; ++q) {
        short8 a8 = gr[q];
        float4 c0 = gc[2 * q], c1 = gc[2 * q + 1];
        s = fmaf(bf2f(a8[0]), c0.x, s);
        s = fmaf(bf2f(a8[1]), c0.y, s);
        s = fmaf(bf2f(a8[2]), c0.z, s);
        s = fmaf(bf2f(a8[3]), c0.w, s);
        s = fmaf(bf2f(a8[4]), c1.x, s);
        s = fmaf(bf2f(a8[5]), c1.y, s);
        s = fmaf(bf2f(a8[6]), c1.z, s);
        s = fmaf(bf2f(a8[7]), c1.w, s);
    }
    float gF = __logf(fmaxf(s, 1e-45f));

    float contrib = gF - 0.5f * o * o - 0.91893853320467274f;
    for (int off = 32; off > 0; off >>= 1) contrib += __shfl_xor(contrib, off, 64);
    if (n == 0) out[b] = ldj[b] + contrib;
}

// ---------------------------------------------------------------------------
extern "C" void kernel_launch(void* const* d_in, const int* in_sizes, int n_in,
                              void* d_out, int out_size, void* d_ws, size_t ws_size,
                              hipStream_t stream)
{
    (void)in_sizes; (void)n_in; (void)out_size; (void)ws_size;

    const float* x = (const float*)d_in[0];
    const float* gates[2] = { (const float*)d_in[28], (const float*)d_in[29] };

    char* ws = (char*)d_ws;
    size_t ofs = 0;
    auto alloc = [&](size_t bytes) { char* p = ws + ofs; ofs += (bytes + 255) & ~(size_t)255; return p; };

    bf16* wn1_all  = (bf16*)alloc((size_t)3 * HIDF * HIDF * 2);   // 24 MB
    bf16* wn2b_all = (bf16*)alloc((size_t)3 * DIMN * HIDF * 2);
    float* wn0T_all = (float*)alloc((size_t)3 * DIMN * HIDF * 4);
    float* eg0_all  = (float*)alloc((size_t)3 * HIDF * 4);
    float* e1_all   = (float*)alloc((size_t)3 * HIDF * 32 * 4);
    float* e2_all   = (float*)alloc((size_t)3 * DIMN * 32 * 4);
    bf16* h0   = (bf16*)alloc((size_t)BATCH * HIDF * 2);
    bf16* part = (bf16*)alloc((size_t)SPLITK * BATCH * HIDF * 2); // 16 MB
    bf16* g0e    = (bf16*)alloc((size_t)BATCH * HIDF * 2);
    bf16* grad1e = (bf16*)alloc((size_t)BATCH * HIDF * 2);
    float* out2p  = (float*)alloc((size_t)NT2 * BATCH * DIMN * 4); // 8 MB
    float* x1     = (float*)alloc((size_t)BATCH * DIMN * 4);
    float* x2     = (float*)alloc((size_t)BATCH * DIMN * 4);
    float* ldj    = (float*)alloc(BATCH * 4);
    float* outp   = (float*)d_out;

    auto W = [&](int f, int i) { return (const float*)d_in[1 + f * 9 + i]; };

    PrepIn p0 = { W(0,0), W(0,1), W(0,3), W(0,4), W(0,6), W(0,7) };
    PrepIn p1 = { W(1,0), W(1,1), W(1,3), W(1,4), W(1,6), W(1,7) };
    PrepIn p2 = { W(2,0), W(2,1), W(2,3), W(2,4), W(2,6), W(2,7) };

    prep_mega<<<dim3(3 * 1040), dim3(256), 0, stream>>>(
        p0, p1, p2, wn0T_all, eg0_all, wn1_all, e1_all, wn2b_all, e2_all);

    gemm0_act<<<dim3(8, BATCH / 16), dim3(256), 0, stream>>>(
        x, wn0T_all, W(0,2), eg0_all, h0, g0e);

    const float* xcur = x;
    float* xnexts[2] = { x1, x2 };

    for (int f = 0; f < 3; ++f) {
        size_t fo1 = (size_t)f * HIDF * HIDF;
        size_t fo2 = (size_t)f * DIMN * HIDF;

        gemm1_part<<<dim3(320), dim3(256), 0, stream>>>(
            h0, wn1_all + fo1, part);

        act_grad_gemm2<<<dim3(HIDF / 64, BATCH / 64), dim3(256), 0, stream>>>(
            part, W(f,5), e1_all + (size_t)f * HIDF * 32, g0e,
            wn2b_all + fo2, grad1e, out2p);

        if (f < 2) {
            tail_gemm0<<<dim3(8, BATCH / 16), dim3(256), 0, stream>>>(
                out2p, W(f,8), e2_all + (size_t)f * DIMN * 32, grad1e,
                xcur, gates[f], xnexts[f], ldj, f,
                wn0T_all + (size_t)(f + 1) * DIMN * HIDF, W(f + 1, 2),
                eg0_all + (size_t)(f + 1) * HIDF, h0, g0e);
            xcur = xnexts[f];
        } else {
            tail_final<<<dim3(BATCH / 4), dim3(256), 0, stream>>>(
                out2p, W(2,8), e2_all + (size_t)2 * DIMN * 32, grad1e, ldj, outp);
        }
    }
}

// Round 11
// 285.239 us; speedup vs baseline: 1.0801x; 1.0801x over previous
//
#include <hip/hip_runtime.h>
#include <hip/hip_bf16.h>
#include <math.h>

// ---------------------------------------------------------------------------
// BNAF flow (DIM=64, HID=32, B=1024).  R26 = R25 resubmitted (prior round
// failed on infra, not kernel). Prep wide rows: each lane owns 8 CONTIGUOUS
// cols per iter (cb = i*512 + lane*8, two adjacent float4 loads) so the
// short8 bf16 store lands at exactly those cols. 8 float4 loads + 4 short8
// stores per row vs 32 scalar loads + 32 scalar 2B stores in R19. All other
// kernels = R19. 13 dispatches.
// ---------------------------------------------------------------------------

#define DIMN 64
#define BATCH 1024
#define HIDF 2048   // DIM*HID
#define SPLITK 4
#define NT2 32      // out2 partial count (= HIDF/64 n-tiles)

typedef __attribute__((ext_vector_type(8))) short short8;
typedef __attribute__((ext_vector_type(4))) float floatx4;
typedef __hip_bfloat16 bf16;

__device__ __forceinline__ float softplusf_(float t) {
    return fmaxf(t, 0.f) + log1pf(__expf(-fabsf(t)));
}

__device__ __forceinline__ float bf2f(short v) {
    union { unsigned u; float f; } x;
    x.u = ((unsigned)(unsigned short)v) << 16;
    return x.f;
}

__device__ __forceinline__ short f2bf_s(float f) {
    bf16 b = __float2bfloat16(f);
    return *(short*)&b;
}

__device__ __forceinline__ void gl_lds16(const void* g, void* l) {
    __builtin_amdgcn_global_load_lds(
        (const __attribute__((address_space(1))) unsigned int*)g,
        (__attribute__((address_space(3))) unsigned int*)l, 16, 0, 0);
}

// tanh + sech^2 from ONE exp.
__device__ __forceinline__ void tanh_sech2_(float p, float& th, float& s2) {
    float t = __expf(-2.f * fabsf(p));
    float opt = 1.f + t;
    float inv = 1.f / opt;
    th = copysignf((1.f - t) * inv, p);
    s2 = 4.f * t * inv * inv;
}

// ---------------------------------------------------------------------------
// prep: W0 rows (64 cols) — scalar (tiny). Transposed f32 output.
// ---------------------------------------------------------------------------
__device__ __forceinline__ void prep_row0(
    const float* __restrict__ W, const float* __restrict__ dw,
    float* __restrict__ wn0T, float* __restrict__ eg0, int r, int lane)
{
    int d = r >> 5;                 // ob=32, ib=1: c0 = d
    const float* Wr = W + (size_t)r * 64;
    float wraw = Wr[lane];
    float wv = (lane < d) ? wraw : ((lane == d) ? __expf(wraw) : 0.f);
    float ss = wv * wv;
    for (int off = 32; off > 0; off >>= 1) ss += __shfl_xor(ss, off, 64);
    float dwr = dw[r];
    float scale = __expf(dwr) / sqrtf(ss);
    wn0T[(size_t)lane * HIDF + r] = scale * wv;
    if (lane == 0) eg0[r] = __expf(dwr - 0.5f * __logf(ss) + Wr[d]);
}

// ---------------------------------------------------------------------------
// prep: wide rows (2048 cols, ib=32). Lane owns 8 contiguous cols per iter:
// cb = i*512 + lane*8 (i<4). Two float4 loads + one short8 store per iter.
// Identical math to R19's prep_row<2048>.
// ---------------------------------------------------------------------------
__device__ __forceinline__ void prep_row_wide(
    const float* __restrict__ W, const float* __restrict__ dw,
    bf16* __restrict__ wn, float* __restrict__ eg,
    int r, int lane, int d)
{
    int c0 = d * 32, c1 = c0 + 32;
    const float* Wr = W + (size_t)r * 2048;

    float4 va[4], vb[4];
    float ss = 0.f;
#pragma unroll
    for (int i = 0; i < 4; ++i) {
        int cb = i * 512 + lane * 8;
        float4 a = *(const float4*)&Wr[cb];
        float4 b = *(const float4*)&Wr[cb + 4];
        a.x = (cb + 0 < c0) ? a.x : ((cb + 0 < c1) ? __expf(a.x) : 0.f);
        a.y = (cb + 1 < c0) ? a.y : ((cb + 1 < c1) ? __expf(a.y) : 0.f);
        a.z = (cb + 2 < c0) ? a.z : ((cb + 2 < c1) ? __expf(a.z) : 0.f);
        a.w = (cb + 3 < c0) ? a.w : ((cb + 3 < c1) ? __expf(a.w) : 0.f);
        b.x = (cb + 4 < c0) ? b.x : ((cb + 4 < c1) ? __expf(b.x) : 0.f);
        b.y = (cb + 5 < c0) ? b.y : ((cb + 5 < c1) ? __expf(b.y) : 0.f);
        b.z = (cb + 6 < c0) ? b.z : ((cb + 6 < c1) ? __expf(b.z) : 0.f);
        b.w = (cb + 7 < c0) ? b.w : ((cb + 7 < c1) ? __expf(b.w) : 0.f);
        va[i] = a;
        vb[i] = b;
        ss += a.x * a.x + a.y * a.y + a.z * a.z + a.w * a.w
            + b.x * b.x + b.y * b.y + b.z * b.z + b.w * b.w;
    }
    for (int off = 32; off > 0; off >>= 1) ss += __shfl_xor(ss, off, 64);

    float dwr = dw[r];
    float scale = __expf(dwr) / sqrtf(ss);
    float logt = dwr - 0.5f * __logf(ss);

#pragma unroll
    for (int i = 0; i < 4; ++i) {
        float4 a = va[i], b = vb[i];
        short8 pk;
        pk[0] = f2bf_s(scale * a.x);
        pk[1] = f2bf_s(scale * a.y);
        pk[2] = f2bf_s(scale * a.z);
        pk[3] = f2bf_s(scale * a.w);
        pk[4] = f2bf_s(scale * b.x);
        pk[5] = f2bf_s(scale * b.y);
        pk[6] = f2bf_s(scale * b.z);
        pk[7] = f2bf_s(scale * b.w);
        *(short8*)((short*)wn + (size_t)r * 2048 + i * 512 + lane * 8) = pk;
    }
    if (lane < 32) eg[(size_t)r * 32 + lane] = __expf(logt + Wr[c0 + lane]);
}

struct PrepIn { const float *W0, *dw0, *W1, *dw1, *W2, *dw2; };

// 4 rows per 256-thread block (one per wave). grid 3 * 1040 = 3120.
__global__ __launch_bounds__(256) void prep_mega(
    PrepIn p0, PrepIn p1, PrepIn p2,
    float* __restrict__ wn0T_all, float* __restrict__ eg0_all,
    bf16* __restrict__ wn1_all, float* __restrict__ e1_all,
    bf16* __restrict__ wn2b_all, float* __restrict__ e2_all)
{
    int blk = blockIdx.x;
    int wave = threadIdx.x >> 6;
    int lane = threadIdx.x & 63;
    int f = blk / 1040;
    int rem = blk - f * 1040;
    int rr = rem * 4 + wave;             // 0..4159 within flow
    PrepIn P = (f == 0) ? p0 : ((f == 1) ? p1 : p2);

    float* wn0T = wn0T_all + (size_t)f * DIMN * HIDF;
    float* eg0  = eg0_all  + (size_t)f * HIDF;
    bf16* wn1   = wn1_all + (size_t)f * HIDF * HIDF;
    float* e1   = e1_all   + (size_t)f * HIDF * 32;
    bf16* wn2b  = wn2b_all + (size_t)f * DIMN * HIDF;
    float* e2   = e2_all   + (size_t)f * DIMN * 32;

    if (rr < HIDF) {
        prep_row0(P.W0, P.dw0, wn0T, eg0, rr, lane);
    } else if (rr < 2 * HIDF) {
        int r = rr - HIDF;
        prep_row_wide(P.W1, P.dw1, wn1, e1, r, lane, r >> 5);   // ob=32
    } else {
        int r = rr - 2 * HIDF;
        prep_row_wide(P.W2, P.dw2, wn2b, e2, r, lane, r);       // ob=1
    }
}

// ---------------------------------------------------------------------------
// gemm0_act: pre0 = x @ wn0T + b0 ; h0 = tanh bf16; g0e = eg0*sech^2 (bf16).
// grid (8, 64), 256 threads.  (R19 form, unchanged)
// ---------------------------------------------------------------------------
__global__ __launch_bounds__(256) void gemm0_act(
    const float* __restrict__ xin, const float* __restrict__ wn0T,
    const float* __restrict__ bias, const float* __restrict__ eg0,
    bf16* __restrict__ h0, bf16* __restrict__ g0e)
{
    __shared__ float xs[16][DIMN];
    int b0 = blockIdx.y * 16;
    {
        const float4* src = (const float4*)(xin + (size_t)b0 * DIMN);
        ((float4*)xs)[threadIdx.x] = src[threadIdx.x];
    }
    __syncthreads();
    int n = blockIdx.x * 256 + threadIdx.x;

    float acc[16];
#pragma unroll
    for (int j = 0; j < 16; ++j) acc[j] = 0.f;

#pragma unroll 4
    for (int c4 = 0; c4 < 16; ++c4) {
        int c = c4 * 4;
        float w0 = wn0T[(size_t)(c + 0) * HIDF + n];
        float w1 = wn0T[(size_t)(c + 1) * HIDF + n];
        float w2 = wn0T[(size_t)(c + 2) * HIDF + n];
        float w3 = wn0T[(size_t)(c + 3) * HIDF + n];
#pragma unroll
        for (int j = 0; j < 16; ++j) {
            float4 x4 = *(const float4*)&xs[j][c];
            acc[j] = fmaf(x4.x, w0, acc[j]);
            acc[j] = fmaf(x4.y, w1, acc[j]);
            acc[j] = fmaf(x4.z, w2, acc[j]);
            acc[j] = fmaf(x4.w, w3, acc[j]);
        }
    }
    float bv = bias[n], egv = eg0[n];
#pragma unroll
    for (int j = 0; j < 16; ++j) {
        float p = acc[j] + bv;
        float th, s2;
        tanh_sech2_(p, th, s2);
        size_t idx = (size_t)(b0 + j) * HIDF + n;
        h0[idx] = __float2bfloat16(th);
        g0e[idx] = __float2bfloat16(egv * s2);
    }
}

// ---------------------------------------------------------------------------
// gemm1_part (R19 form): 128x128 tile, LPT live triangular schedule. grid 320.
// ---------------------------------------------------------------------------
__constant__ unsigned char G1_JN[40] = {
    3,4,5,6,7,7,8,8,9,9,10,10,11,11,11,12,12,12,13,13,13,14,14,14,
    15,15,15,15, 2,6,10,14, 1,5,9,13, 0,4,8,12 };
__constant__ unsigned char G1_KZ[40] = {
    0,0,0,0,0,1,0,1,0,1, 0, 1, 0, 1, 2, 0, 1, 2, 0, 1, 2, 0, 1, 2,
     0, 1, 2, 3, 0,1, 2, 3, 0,1,2,3, 0,1,2,3 };

#define G1BK 64
__global__ __launch_bounds__(256) void gemm1_part(
    const bf16* __restrict__ A, const bf16* __restrict__ B,
    bf16* __restrict__ part)
{
    const int K = HIDF, N = HIDF;
    int pr = blockIdx.x >> 3;
    int my = blockIdx.x & 7;
    int jn = G1_JN[pr];
    int kz = G1_KZ[pr];
    int kbase = kz * (K / SPLITK);
    int kend = (jn + 1) * 128 - kbase;
    if (kend > K / SPLITK) kend = K / SPLITK;

    __shared__ short As[128 * 64];
    __shared__ short Bs[128 * 64];
    int tid = threadIdx.x;
    int lane = tid & 63;
    int wave = tid >> 6;
    int n0 = jn * 128;
    int m0 = my * 128;
    int wr = wave >> 1;
    int wc = wave & 1;
    int rf = lane & 15;
    int q = lane >> 4;

    const char* agp[4];
    const char* bgp[4];
    char* alds[4];
    char* blds[4];
#pragma unroll
    for (int s = 0; s < 4; ++s) {
        int c = tid + s * 256;
        int row = c >> 3;
        int kc = (c & 7) ^ (row & 7);
        agp[s] = (const char*)A + ((size_t)(m0 + row) * K + kbase) * 2 + kc * 16;
        bgp[s] = (const char*)B + ((size_t)(n0 + row) * K + kbase) * 2 + kc * 16;
        alds[s] = (char*)As + c * 16;
        blds[s] = (char*)Bs + c * 16;
    }

    floatx4 acc[4][4];
#pragma unroll
    for (int i = 0; i < 4; ++i)
#pragma unroll
        for (int j = 0; j < 4; ++j) acc[i][j] = (floatx4){0.f, 0.f, 0.f, 0.f};

    int rowA0 = wr * 64 + rf;
    int rowB0 = wc * 64 + rf;

    for (int k0 = 0; k0 < kend; k0 += G1BK) {
        size_t kb = (size_t)k0 * 2;
        __syncthreads();
#pragma unroll
        for (int s = 0; s < 4; ++s) {
            gl_lds16(agp[s] + kb, alds[s]);
            gl_lds16(bgp[s] + kb, blds[s]);
        }
        __syncthreads();

#pragma unroll
        for (int s = 0; s < 2; ++s) {
            short8 af[4], bfv[4];
#pragma unroll
            for (int i = 0; i < 4; ++i) {
                int row = rowA0 + i * 16;
                af[i] = *(const short8*)&As[row * 64 + (((s * 4 + q) ^ (row & 7)) * 8)];
            }
#pragma unroll
            for (int j = 0; j < 4; ++j) {
                int row = rowB0 + j * 16;
                bfv[j] = *(const short8*)&Bs[row * 64 + (((s * 4 + q) ^ (row & 7)) * 8)];
            }
#pragma unroll
            for (int i = 0; i < 4; ++i)
#pragma unroll
                for (int j = 0; j < 4; ++j)
                    acc[i][j] = __builtin_amdgcn_mfma_f32_16x16x32_bf16(af[i], bfv[j], acc[i][j], 0, 0, 0);
        }
    }

    bf16* pk = part + (size_t)kz * BATCH * HIDF;
    int col = lane & 15;
    int rq = (lane >> 4) * 4;
#pragma unroll
    for (int i = 0; i < 4; ++i) {
#pragma unroll
        for (int j = 0; j < 4; ++j) {
            int n = n0 + wc * 64 + j * 16 + col;
#pragma unroll
            for (int r = 0; r < 4; ++r) {
                int m = m0 + wr * 64 + i * 16 + rq + r;
                pk[(size_t)m * N + n] = __float2bfloat16(acc[i][j][r]);
            }
        }
    }
}

// ---------------------------------------------------------------------------
// act_grad_gemm2 (R19 branch-free form, unchanged).
// ---------------------------------------------------------------------------
__global__ __launch_bounds__(256) void act_grad_gemm2(
    const bf16* __restrict__ part, const float* __restrict__ bias,
    const float* __restrict__ e1, const bf16* __restrict__ g0e,
    const bf16* __restrict__ wn2b,
    bf16* __restrict__ grad1e, float* __restrict__ out2p)
{
    __shared__ char smem[17408 + 8704 + 8192];
    float* g0s = (float*)smem;
    short* h1s = (short*)(smem + 17408);
    short* Bs2 = (short*)(smem + 17408 + 8704);

    int tid = threadIdx.x;
    int lane = tid & 63;
    int wave = tid >> 6;
    int bx = blockIdx.x;
    int n0 = bx * 64;
    int b0 = blockIdx.y * 64;
    int np = (bx >> 3) + 1;

    {
        int c0c = tid, c1c = tid + 256;
        int r0 = c0c >> 3, k0c = (c0c & 7) ^ (r0 & 7);
        int r1 = c1c >> 3, k1c = (c1c & 7) ^ (r1 & 7);
        gl_lds16((const char*)wn2b + ((size_t)r0 * HIDF + n0) * 2 + k0c * 16,
                 (char*)Bs2 + c0c * 16);
        gl_lds16((const char*)wn2b + ((size_t)r1 * HIDF + n0) * 2 + k1c * 16,
                 (char*)Bs2 + c1c * 16);
    }

    for (int s = tid; s < 512; s += 256) {
        int row = s >> 3, c8 = s & 7;
        short8 v = *(const short8*)((const short*)g0e +
                                    (size_t)(b0 + row) * HIDF + n0 + c8 * 8);
        float4 lo = { bf2f(v[0]), bf2f(v[1]), bf2f(v[2]), bf2f(v[3]) };
        float4 hi = { bf2f(v[4]), bf2f(v[5]), bf2f(v[6]), bf2f(v[7]) };
        *(float4*)&g0s[row * 68 + c8 * 8] = lo;
        *(float4*)&g0s[row * 68 + c8 * 8 + 4] = hi;
    }

    int g = tid >> 6;
    int nl = tid & 63;
    int n = n0 + nl;

    float4 er[8];
    const float4* e1r = (const float4*)(e1 + (size_t)n * 32);
#pragma unroll
    for (int qq = 0; qq < 8; ++qq) er[qq] = e1r[qq];

    float bv = bias[n];
    int kb2 = nl & 32;
    const bf16* pp0 = part;
    const bf16* pp1 = (np > 1) ? part + (size_t)1 * BATCH * HIDF : part;
    const bf16* pp2 = (np > 2) ? part + (size_t)2 * BATCH * HIDF : part;
    const bf16* pp3 = (np > 3) ? part + (size_t)3 * BATCH * HIDF : part;
    float m1 = (np > 1) ? 1.f : 0.f;
    float m2 = (np > 2) ? 1.f : 0.f;
    float m3 = (np > 3) ? 1.f : 0.f;

    __syncthreads();

#pragma unroll
    for (int t = 0; t < 16; ++t) {
        int bl = g * 16 + t;
        int b = b0 + bl;
        size_t idx = (size_t)b * HIDF + n;
        float l0 = __bfloat162float(pp0[idx]);
        float l1 = __bfloat162float(pp1[idx]);
        float l2 = __bfloat162float(pp2[idx]);
        float l3 = __bfloat162float(pp3[idx]);
        float pre = bv + l0;
        pre = fmaf(m1, l1, pre);
        pre = fmaf(m2, l2, pre);
        pre = fmaf(m3, l3, pre);
        float th, s2;
        tanh_sech2_(pre, th, s2);
        const float* g0row = &g0s[bl * 68 + kb2];
        float dot = 0.f;
#pragma unroll
        for (int qq = 0; qq < 8; ++qq) {
            float4 gv = *(const float4*)&g0row[qq * 4];
            dot = fmaf(gv.x, er[qq].x, dot);
            dot = fmaf(gv.y, er[qq].y, dot);
            dot = fmaf(gv.z, er[qq].z, dot);
            dot = fmaf(gv.w, er[qq].w, dot);
        }
        bf16 thb = __float2bfloat16(th);
        h1s[bl * 68 + nl] = *(const short*)&thb;
        grad1e[idx] = __float2bfloat16(dot * s2);
    }
    __syncthreads();

    int rf = lane & 15;
    int q = lane >> 4;
    floatx4 acc2[4];
#pragma unroll
    for (int j = 0; j < 4; ++j) acc2[j] = (floatx4){0.f, 0.f, 0.f, 0.f};

#pragma unroll
    for (int s = 0; s < 2; ++s) {
        int rowa = wave * 16 + rf;
        short8 af = *(const short8*)&h1s[rowa * 68 + s * 32 + q * 8];
#pragma unroll
        for (int j = 0; j < 4; ++j) {
            int rowb = j * 16 + rf;
            int cp = (s * 4 + q) ^ (rowb & 7);
            short8 bfv = *(const short8*)&Bs2[rowb * 64 + cp * 8];
            acc2[j] = __builtin_amdgcn_mfma_f32_16x16x32_bf16(af, bfv, acc2[j], 0, 0, 0);
        }
    }

    float* outk = out2p + (size_t)bx * BATCH * DIMN;
    int col = lane & 15;
    int rq = (lane >> 4) * 4;
#pragma unroll
    for (int j = 0; j < 4; ++j) {
#pragma unroll
        for (int r = 0; r < 4; ++r) {
            int m = b0 + wave * 16 + rq + r;
            outk[(size_t)m * DIMN + j * 16 + col] = acc2[j][r];
        }
    }
}

// ---------------------------------------------------------------------------
// tail_trans (R19 form, unchanged): one wave per batch row.
// ---------------------------------------------------------------------------
__global__ __launch_bounds__(256) void tail_trans(
    const float* __restrict__ out2p, const float* __restrict__ b2,
    const float* __restrict__ e2, const bf16* __restrict__ grad1e,
    const float* __restrict__ x_cur, const float* __restrict__ gate,
    float* __restrict__ x_next, float* __restrict__ ldj, int accum_ldj)
{
    int tid = threadIdx.x;
    int b = blockIdx.x * 4 + (tid >> 6);
    int n = tid & 63;

    float o = b2[n];
#pragma unroll
    for (int p = 0; p < NT2; ++p)
        o += out2p[(size_t)p * BATCH * DIMN + (size_t)b * DIMN + n];

    float gt = gate[0];
    float sg = 1.f / (1.f + __expf(-gt));
    float xo = sg * o + (1.f - sg) * x_cur[(size_t)b * DIMN + n];
    x_next[(size_t)b * DIMN + (63 - n)] = xo;

    const short8* gr = (const short8*)((const short*)grad1e + (size_t)b * HIDF + n * 32);
    const float4* gc = (const float4*)(e2 + n * 32);
    float s = 0.f;
#pragma unroll
    for (int q = 0; q < 4; ++q) {
        short8 a8 = gr[q];
        float4 c0 = gc[2 * q], c1 = gc[2 * q + 1];
        s = fmaf(bf2f(a8[0]), c0.x, s);
        s = fmaf(bf2f(a8[1]), c0.y, s);
        s = fmaf(bf2f(a8[2]), c0.z, s);
        s = fmaf(bf2f(a8[3]), c0.w, s);
        s = fmaf(bf2f(a8[4]), c1.x, s);
        s = fmaf(bf2f(a8[5]), c1.y, s);
        s = fmaf(bf2f(a8[6]), c1.z, s);
        s = fmaf(bf2f(a8[7]), c1.w, s);
    }
    float gF = __logf(fmaxf(s, 1e-45f));
    float contrib = softplusf_(gF + gt) - softplusf_(gt);
    for (int off = 32; off > 0; off >>= 1) contrib += __shfl_xor(contrib, off, 64);
    if (n == 0) ldj[b] = accum_ldj ? (ldj[b] + contrib) : contrib;
}

// ---------------------------------------------------------------------------
// tail_final (R19 form, unchanged).
// ---------------------------------------------------------------------------
__global__ __launch_bounds__(256) void tail_final(
    const float* __restrict__ out2p, const float* __restrict__ b2,
    const float* __restrict__ e2, const bf16* __restrict__ grad1e,
    const float* __restrict__ ldj, float* __restrict__ out)
{
    int tid = threadIdx.x;
    int b = blockIdx.x * 4 + (tid >> 6);
    int n = tid & 63;

    float o = b2[n];
#pragma unroll
    for (int p = 0; p < NT2; ++p)
        o += out2p[(size_t)p * BATCH * DIMN + (size_t)b * DIMN + n];

    const short8* gr = (const short8*)((const short*)grad1e + (size_t)b * HIDF + n * 32);
    const float4* gc = (const float4*)(e2 + n * 32);
    float s = 0.f;
#pragma unroll
    for (int q = 0; q < 4; ++q) {
        short8 a8 = gr[q];
        float4 c0 = gc[2 * q], c1 = gc[2 * q + 1];
        s = fmaf(bf2f(a8[0]), c0.x, s);
        s = fmaf(bf2f(a8[1]), c0.y, s);
        s = fmaf(bf2f(a8[2]), c0.z, s);
        s = fmaf(bf2f(a8[3]), c0.w, s);
        s = fmaf(bf2f(a8[4]), c1.x, s);
        s = fmaf(bf2f(a8[5]), c1.y, s);
        s = fmaf(bf2f(a8[6]), c1.z, s);
        s = fmaf(bf2f(a8[7]), c1.w, s);
    }
    float gF = __logf(fmaxf(s, 1e-45f));

    float contrib = gF - 0.5f * o * o - 0.91893853320467274f;
    for (int off = 32; off > 0; off >>= 1) contrib += __shfl_xor(contrib, off, 64);
    if (n == 0) out[b] = ldj[b] + contrib;
}

// ---------------------------------------------------------------------------
extern "C" void kernel_launch(void* const* d_in, const int* in_sizes, int n_in,
                              void* d_out, int out_size, void* d_ws, size_t ws_size,
                              hipStream_t stream)
{
    (void)in_sizes; (void)n_in; (void)out_size; (void)ws_size;

    const float* x = (const float*)d_in[0];
    const float* gates[2] = { (const float*)d_in[28], (const float*)d_in[29] };

    char* ws = (char*)d_ws;
    size_t ofs = 0;
    auto alloc = [&](size_t bytes) { char* p = ws + ofs; ofs += (bytes + 255) & ~(size_t)255; return p; };

    bf16* wn1_all  = (bf16*)alloc((size_t)3 * HIDF * HIDF * 2);   // 24 MB
    bf16* wn2b_all = (bf16*)alloc((size_t)3 * DIMN * HIDF * 2);
    float* wn0T_all = (float*)alloc((size_t)3 * DIMN * HIDF * 4);
    float* eg0_all  = (float*)alloc((size_t)3 * HIDF * 4);
    float* e1_all   = (float*)alloc((size_t)3 * HIDF * 32 * 4);
    float* e2_all   = (float*)alloc((size_t)3 * DIMN * 32 * 4);
    bf16* h0   = (bf16*)alloc((size_t)BATCH * HIDF * 2);
    bf16* part = (bf16*)alloc((size_t)SPLITK * BATCH * HIDF * 2); // 16 MB
    bf16* g0e    = (bf16*)alloc((size_t)BATCH * HIDF * 2);
    bf16* grad1e = (bf16*)alloc((size_t)BATCH * HIDF * 2);
    float* out2p  = (float*)alloc((size_t)NT2 * BATCH * DIMN * 4); // 8 MB
    float* x1     = (float*)alloc((size_t)BATCH * DIMN * 4);
    float* x2     = (float*)alloc((size_t)BATCH * DIMN * 4);
    float* ldj    = (float*)alloc(BATCH * 4);
    float* outp   = (float*)d_out;

    auto W = [&](int f, int i) { return (const float*)d_in[1 + f * 9 + i]; };

    PrepIn p0 = { W(0,0), W(0,1), W(0,3), W(0,4), W(0,6), W(0,7) };
    PrepIn p1 = { W(1,0), W(1,1), W(1,3), W(1,4), W(1,6), W(1,7) };
    PrepIn p2 = { W(2,0), W(2,1), W(2,3), W(2,4), W(2,6), W(2,7) };

    prep_mega<<<dim3(3 * 1040), dim3(256), 0, stream>>>(
        p0, p1, p2, wn0T_all, eg0_all, wn1_all, e1_all, wn2b_all, e2_all);

    gemm0_act<<<dim3(8, BATCH / 16), dim3(256), 0, stream>>>(
        x, wn0T_all, W(0,2), eg0_all, h0, g0e);

    const float* xcur = x;
    float* xnexts[2] = { x1, x2 };

    for (int f = 0; f < 3; ++f) {
        size_t fo1 = (size_t)f * HIDF * HIDF;
        size_t fo2 = (size_t)f * DIMN * HIDF;

        gemm1_part<<<dim3(320), dim3(256), 0, stream>>>(
            h0, wn1_all + fo1, part);

        act_grad_gemm2<<<dim3(HIDF / 64, BATCH / 64), dim3(256), 0, stream>>>(
            part, W(f,5), e1_all + (size_t)f * HIDF * 32, g0e,
            wn2b_all + fo2, grad1e, out2p);

        if (f < 2) {
            tail_trans<<<dim3(BATCH / 4), dim3(256), 0, stream>>>(
                out2p, W(f,8), e2_all + (size_t)f * DIMN * 32, grad1e,
                xcur, gates[f], xnexts[f], ldj, f);

            gemm0_act<<<dim3(8, BATCH / 16), dim3(256), 0, stream>>>(
                xnexts[f], wn0T_all + (size_t)(f + 1) * DIMN * HIDF, W(f + 1, 2),
                eg0_all + (size_t)(f + 1) * HIDF, h0, g0e);

            xcur = xnexts[f];
        } else {
            tail_final<<<dim3(BATCH / 4), dim3(256), 0, stream>>>(
                out2p, W(2,8), e2_all + (size_t)2 * DIMN * 32, grad1e, ldj, outp);
        }
    }
}

// Round 12
// 277.009 us; speedup vs baseline: 1.1122x; 1.0297x over previous
//
#include <hip/hip_runtime.h>
#include <hip/hip_bf16.h>
#include <math.h>

// ---------------------------------------------------------------------------
// BNAF flow (DIM=64, HID=32, B=1024).  R27: R26 base (285us) + occupancy
// fixes: gemm1 retiled 128x128 -> 64m x 128n (grid 320 -> 640 = 2.5
// blocks/CU so staging barriers overlap with a co-resident block, m114);
// tails 256x256thr -> 512x128thr (2 rows/block, 2 blocks/CU). Same math,
// same LPT schedule, same staged bytes. 13 dispatches.
// ---------------------------------------------------------------------------

#define DIMN 64
#define BATCH 1024
#define HIDF 2048   // DIM*HID
#define SPLITK 4
#define NT2 32      // out2 partial count (= HIDF/64 n-tiles)

typedef __attribute__((ext_vector_type(8))) short short8;
typedef __attribute__((ext_vector_type(4))) float floatx4;
typedef __hip_bfloat16 bf16;

__device__ __forceinline__ float softplusf_(float t) {
    return fmaxf(t, 0.f) + log1pf(__expf(-fabsf(t)));
}

__device__ __forceinline__ float bf2f(short v) {
    union { unsigned u; float f; } x;
    x.u = ((unsigned)(unsigned short)v) << 16;
    return x.f;
}

__device__ __forceinline__ short f2bf_s(float f) {
    bf16 b = __float2bfloat16(f);
    return *(short*)&b;
}

__device__ __forceinline__ void gl_lds16(const void* g, void* l) {
    __builtin_amdgcn_global_load_lds(
        (const __attribute__((address_space(1))) unsigned int*)g,
        (__attribute__((address_space(3))) unsigned int*)l, 16, 0, 0);
}

// tanh + sech^2 from ONE exp.
__device__ __forceinline__ void tanh_sech2_(float p, float& th, float& s2) {
    float t = __expf(-2.f * fabsf(p));
    float opt = 1.f + t;
    float inv = 1.f / opt;
    th = copysignf((1.f - t) * inv, p);
    s2 = 4.f * t * inv * inv;
}

// ---------------------------------------------------------------------------
// prep: W0 rows (64 cols) — scalar (tiny). Transposed f32 output.
// ---------------------------------------------------------------------------
__device__ __forceinline__ void prep_row0(
    const float* __restrict__ W, const float* __restrict__ dw,
    float* __restrict__ wn0T, float* __restrict__ eg0, int r, int lane)
{
    int d = r >> 5;                 // ob=32, ib=1: c0 = d
    const float* Wr = W + (size_t)r * 64;
    float wraw = Wr[lane];
    float wv = (lane < d) ? wraw : ((lane == d) ? __expf(wraw) : 0.f);
    float ss = wv * wv;
    for (int off = 32; off > 0; off >>= 1) ss += __shfl_xor(ss, off, 64);
    float dwr = dw[r];
    float scale = __expf(dwr) / sqrtf(ss);
    wn0T[(size_t)lane * HIDF + r] = scale * wv;
    if (lane == 0) eg0[r] = __expf(dwr - 0.5f * __logf(ss) + Wr[d]);
}

// ---------------------------------------------------------------------------
// prep: wide rows (2048 cols, ib=32). Lane owns 8 contiguous cols per iter:
// cb = i*512 + lane*8 (i<4). Two float4 loads + one short8 store per iter.
// ---------------------------------------------------------------------------
__device__ __forceinline__ void prep_row_wide(
    const float* __restrict__ W, const float* __restrict__ dw,
    bf16* __restrict__ wn, float* __restrict__ eg,
    int r, int lane, int d)
{
    int c0 = d * 32, c1 = c0 + 32;
    const float* Wr = W + (size_t)r * 2048;

    float4 va[4], vb[4];
    float ss = 0.f;
#pragma unroll
    for (int i = 0; i < 4; ++i) {
        int cb = i * 512 + lane * 8;
        float4 a = *(const float4*)&Wr[cb];
        float4 b = *(const float4*)&Wr[cb + 4];
        a.x = (cb + 0 < c0) ? a.x : ((cb + 0 < c1) ? __expf(a.x) : 0.f);
        a.y = (cb + 1 < c0) ? a.y : ((cb + 1 < c1) ? __expf(a.y) : 0.f);
        a.z = (cb + 2 < c0) ? a.z : ((cb + 2 < c1) ? __expf(a.z) : 0.f);
        a.w = (cb + 3 < c0) ? a.w : ((cb + 3 < c1) ? __expf(a.w) : 0.f);
        b.x = (cb + 4 < c0) ? b.x : ((cb + 4 < c1) ? __expf(b.x) : 0.f);
        b.y = (cb + 5 < c0) ? b.y : ((cb + 5 < c1) ? __expf(b.y) : 0.f);
        b.z = (cb + 6 < c0) ? b.z : ((cb + 6 < c1) ? __expf(b.z) : 0.f);
        b.w = (cb + 7 < c0) ? b.w : ((cb + 7 < c1) ? __expf(b.w) : 0.f);
        va[i] = a;
        vb[i] = b;
        ss += a.x * a.x + a.y * a.y + a.z * a.z + a.w * a.w
            + b.x * b.x + b.y * b.y + b.z * b.z + b.w * b.w;
    }
    for (int off = 32; off > 0; off >>= 1) ss += __shfl_xor(ss, off, 64);

    float dwr = dw[r];
    float scale = __expf(dwr) / sqrtf(ss);
    float logt = dwr - 0.5f * __logf(ss);

#pragma unroll
    for (int i = 0; i < 4; ++i) {
        float4 a = va[i], b = vb[i];
        short8 pk;
        pk[0] = f2bf_s(scale * a.x);
        pk[1] = f2bf_s(scale * a.y);
        pk[2] = f2bf_s(scale * a.z);
        pk[3] = f2bf_s(scale * a.w);
        pk[4] = f2bf_s(scale * b.x);
        pk[5] = f2bf_s(scale * b.y);
        pk[6] = f2bf_s(scale * b.z);
        pk[7] = f2bf_s(scale * b.w);
        *(short8*)((short*)wn + (size_t)r * 2048 + i * 512 + lane * 8) = pk;
    }
    if (lane < 32) eg[(size_t)r * 32 + lane] = __expf(logt + Wr[c0 + lane]);
}

struct PrepIn { const float *W0, *dw0, *W1, *dw1, *W2, *dw2; };

// 4 rows per 256-thread block (one per wave). grid 3 * 1040 = 3120.
__global__ __launch_bounds__(256) void prep_mega(
    PrepIn p0, PrepIn p1, PrepIn p2,
    float* __restrict__ wn0T_all, float* __restrict__ eg0_all,
    bf16* __restrict__ wn1_all, float* __restrict__ e1_all,
    bf16* __restrict__ wn2b_all, float* __restrict__ e2_all)
{
    int blk = blockIdx.x;
    int wave = threadIdx.x >> 6;
    int lane = threadIdx.x & 63;
    int f = blk / 1040;
    int rem = blk - f * 1040;
    int rr = rem * 4 + wave;             // 0..4159 within flow
    PrepIn P = (f == 0) ? p0 : ((f == 1) ? p1 : p2);

    float* wn0T = wn0T_all + (size_t)f * DIMN * HIDF;
    float* eg0  = eg0_all  + (size_t)f * HIDF;
    bf16* wn1   = wn1_all + (size_t)f * HIDF * HIDF;
    float* e1   = e1_all   + (size_t)f * HIDF * 32;
    bf16* wn2b  = wn2b_all + (size_t)f * DIMN * HIDF;
    float* e2   = e2_all   + (size_t)f * DIMN * 32;

    if (rr < HIDF) {
        prep_row0(P.W0, P.dw0, wn0T, eg0, rr, lane);
    } else if (rr < 2 * HIDF) {
        int r = rr - HIDF;
        prep_row_wide(P.W1, P.dw1, wn1, e1, r, lane, r >> 5);   // ob=32
    } else {
        int r = rr - 2 * HIDF;
        prep_row_wide(P.W2, P.dw2, wn2b, e2, r, lane, r);       // ob=1
    }
}

// ---------------------------------------------------------------------------
// gemm0_act: pre0 = x @ wn0T + b0 ; h0 = tanh bf16; g0e = eg0*sech^2 (bf16).
// grid (8, 64), 256 threads.  (R19 form, unchanged)
// ---------------------------------------------------------------------------
__global__ __launch_bounds__(256) void gemm0_act(
    const float* __restrict__ xin, const float* __restrict__ wn0T,
    const float* __restrict__ bias, const float* __restrict__ eg0,
    bf16* __restrict__ h0, bf16* __restrict__ g0e)
{
    __shared__ float xs[16][DIMN];
    int b0 = blockIdx.y * 16;
    {
        const float4* src = (const float4*)(xin + (size_t)b0 * DIMN);
        ((float4*)xs)[threadIdx.x] = src[threadIdx.x];
    }
    __syncthreads();
    int n = blockIdx.x * 256 + threadIdx.x;

    float acc[16];
#pragma unroll
    for (int j = 0; j < 16; ++j) acc[j] = 0.f;

#pragma unroll 4
    for (int c4 = 0; c4 < 16; ++c4) {
        int c = c4 * 4;
        float w0 = wn0T[(size_t)(c + 0) * HIDF + n];
        float w1 = wn0T[(size_t)(c + 1) * HIDF + n];
        float w2 = wn0T[(size_t)(c + 2) * HIDF + n];
        float w3 = wn0T[(size_t)(c + 3) * HIDF + n];
#pragma unroll
        for (int j = 0; j < 16; ++j) {
            float4 x4 = *(const float4*)&xs[j][c];
            acc[j] = fmaf(x4.x, w0, acc[j]);
            acc[j] = fmaf(x4.y, w1, acc[j]);
            acc[j] = fmaf(x4.z, w2, acc[j]);
            acc[j] = fmaf(x4.w, w3, acc[j]);
        }
    }
    float bv = bias[n], egv = eg0[n];
#pragma unroll
    for (int j = 0; j < 16; ++j) {
        float p = acc[j] + bv;
        float th, s2;
        tanh_sech2_(p, th, s2);
        size_t idx = (size_t)(b0 + j) * HIDF + n;
        h0[idx] = __float2bfloat16(th);
        g0e[idx] = __float2bfloat16(egv * s2);
    }
}

// ---------------------------------------------------------------------------
// gemm1_part (R27): 64m x 128n tile, LPT live triangular schedule.
// grid 640 = 40 pairs x 16 m-tiles -> 2.5 blocks/CU (barrier overlap).
// Per wave: (wr = m-half 32 rows, wc = n-half 64 cols), acc[2][4].
// LDS: A 8KB + B 16KB = 24KB.
// ---------------------------------------------------------------------------
__constant__ unsigned char G1_JN[40] = {
    3,4,5,6,7,7,8,8,9,9,10,10,11,11,11,12,12,12,13,13,13,14,14,14,
    15,15,15,15, 2,6,10,14, 1,5,9,13, 0,4,8,12 };
__constant__ unsigned char G1_KZ[40] = {
    0,0,0,0,0,1,0,1,0,1, 0, 1, 0, 1, 2, 0, 1, 2, 0, 1, 2, 0, 1, 2,
     0, 1, 2, 3, 0,1, 2, 3, 0,1,2,3, 0,1,2,3 };

#define G1BK 64
__global__ __launch_bounds__(256) void gemm1_part(
    const bf16* __restrict__ A, const bf16* __restrict__ B,
    bf16* __restrict__ part)
{
    const int K = HIDF, N = HIDF;
    int pr = blockIdx.x >> 4;      // pair index (LPT order)
    int my = blockIdx.x & 15;      // m-tile (64 rows each)
    int jn = G1_JN[pr];
    int kz = G1_KZ[pr];
    int kbase = kz * (K / SPLITK);
    int kend = (jn + 1) * 128 - kbase;
    if (kend > K / SPLITK) kend = K / SPLITK;

    __shared__ short As[64 * 64];    // 8 KB  [64 m][64 k] swizzled
    __shared__ short Bs[128 * 64];   // 16 KB [128 n][64 k] swizzled
    int tid = threadIdx.x;
    int lane = tid & 63;
    int wave = tid >> 6;
    int n0 = jn * 128;
    int m0 = my * 64;
    int wr = wave >> 1;   // m half (32 rows)
    int wc = wave & 1;    // n half (64 cols)
    int rf = lane & 15;
    int q = lane >> 4;

    // A staging: 2 rounds (rows 0..63); B staging: 4 rounds (rows 0..127)
    const char* agp[2];
    char* alds[2];
#pragma unroll
    for (int s = 0; s < 2; ++s) {
        int c = tid + s * 256;
        int row = c >> 3;
        int kc = (c & 7) ^ (row & 7);
        agp[s] = (const char*)A + ((size_t)(m0 + row) * K + kbase) * 2 + kc * 16;
        alds[s] = (char*)As + c * 16;
    }
    const char* bgp[4];
    char* blds[4];
#pragma unroll
    for (int s = 0; s < 4; ++s) {
        int c = tid + s * 256;
        int row = c >> 3;
        int kc = (c & 7) ^ (row & 7);
        bgp[s] = (const char*)B + ((size_t)(n0 + row) * K + kbase) * 2 + kc * 16;
        blds[s] = (char*)Bs + c * 16;
    }

    floatx4 acc[2][4];
#pragma unroll
    for (int i = 0; i < 2; ++i)
#pragma unroll
        for (int j = 0; j < 4; ++j) acc[i][j] = (floatx4){0.f, 0.f, 0.f, 0.f};

    int rowA0 = wr * 32 + rf;
    int rowB0 = wc * 64 + rf;

    for (int k0 = 0; k0 < kend; k0 += G1BK) {
        size_t kb = (size_t)k0 * 2;
        __syncthreads();
#pragma unroll
        for (int s = 0; s < 2; ++s) gl_lds16(agp[s] + kb, alds[s]);
#pragma unroll
        for (int s = 0; s < 4; ++s) gl_lds16(bgp[s] + kb, blds[s]);
        __syncthreads();

#pragma unroll
        for (int s = 0; s < 2; ++s) {
            short8 af[2], bfv[4];
#pragma unroll
            for (int i = 0; i < 2; ++i) {
                int row = rowA0 + i * 16;
                af[i] = *(const short8*)&As[row * 64 + (((s * 4 + q) ^ (row & 7)) * 8)];
            }
#pragma unroll
            for (int j = 0; j < 4; ++j) {
                int row = rowB0 + j * 16;
                bfv[j] = *(const short8*)&Bs[row * 64 + (((s * 4 + q) ^ (row & 7)) * 8)];
            }
#pragma unroll
            for (int i = 0; i < 2; ++i)
#pragma unroll
                for (int j = 0; j < 4; ++j)
                    acc[i][j] = __builtin_amdgcn_mfma_f32_16x16x32_bf16(af[i], bfv[j], acc[i][j], 0, 0, 0);
        }
    }

    bf16* pk = part + (size_t)kz * BATCH * HIDF;
    int col = lane & 15;
    int rq = (lane >> 4) * 4;
#pragma unroll
    for (int i = 0; i < 2; ++i) {
#pragma unroll
        for (int j = 0; j < 4; ++j) {
            int n = n0 + wc * 64 + j * 16 + col;
#pragma unroll
            for (int r = 0; r < 4; ++r) {
                int m = m0 + wr * 32 + i * 16 + rq + r;
                pk[(size_t)m * N + n] = __float2bfloat16(acc[i][j][r]);
            }
        }
    }
}

// ---------------------------------------------------------------------------
// act_grad_gemm2 (R19 branch-free form, unchanged).
// ---------------------------------------------------------------------------
__global__ __launch_bounds__(256) void act_grad_gemm2(
    const bf16* __restrict__ part, const float* __restrict__ bias,
    const float* __restrict__ e1, const bf16* __restrict__ g0e,
    const bf16* __restrict__ wn2b,
    bf16* __restrict__ grad1e, float* __restrict__ out2p)
{
    __shared__ char smem[17408 + 8704 + 8192];
    float* g0s = (float*)smem;
    short* h1s = (short*)(smem + 17408);
    short* Bs2 = (short*)(smem + 17408 + 8704);

    int tid = threadIdx.x;
    int lane = tid & 63;
    int wave = tid >> 6;
    int bx = blockIdx.x;
    int n0 = bx * 64;
    int b0 = blockIdx.y * 64;
    int np = (bx >> 3) + 1;

    {
        int c0c = tid, c1c = tid + 256;
        int r0 = c0c >> 3, k0c = (c0c & 7) ^ (r0 & 7);
        int r1 = c1c >> 3, k1c = (c1c & 7) ^ (r1 & 7);
        gl_lds16((const char*)wn2b + ((size_t)r0 * HIDF + n0) * 2 + k0c * 16,
                 (char*)Bs2 + c0c * 16);
        gl_lds16((const char*)wn2b + ((size_t)r1 * HIDF + n0) * 2 + k1c * 16,
                 (char*)Bs2 + c1c * 16);
    }

    for (int s = tid; s < 512; s += 256) {
        int row = s >> 3, c8 = s & 7;
        short8 v = *(const short8*)((const short*)g0e +
                                    (size_t)(b0 + row) * HIDF + n0 + c8 * 8);
        float4 lo = { bf2f(v[0]), bf2f(v[1]), bf2f(v[2]), bf2f(v[3]) };
        float4 hi = { bf2f(v[4]), bf2f(v[5]), bf2f(v[6]), bf2f(v[7]) };
        *(float4*)&g0s[row * 68 + c8 * 8] = lo;
        *(float4*)&g0s[row * 68 + c8 * 8 + 4] = hi;
    }

    int g = tid >> 6;
    int nl = tid & 63;
    int n = n0 + nl;

    float4 er[8];
    const float4* e1r = (const float4*)(e1 + (size_t)n * 32);
#pragma unroll
    for (int qq = 0; qq < 8; ++qq) er[qq] = e1r[qq];

    float bv = bias[n];
    int kb2 = nl & 32;
    const bf16* pp0 = part;
    const bf16* pp1 = (np > 1) ? part + (size_t)1 * BATCH * HIDF : part;
    const bf16* pp2 = (np > 2) ? part + (size_t)2 * BATCH * HIDF : part;
    const bf16* pp3 = (np > 3) ? part + (size_t)3 * BATCH * HIDF : part;
    float m1 = (np > 1) ? 1.f : 0.f;
    float m2 = (np > 2) ? 1.f : 0.f;
    float m3 = (np > 3) ? 1.f : 0.f;

    __syncthreads();

#pragma unroll
    for (int t = 0; t < 16; ++t) {
        int bl = g * 16 + t;
        int b = b0 + bl;
        size_t idx = (size_t)b * HIDF + n;
        float l0 = __bfloat162float(pp0[idx]);
        float l1 = __bfloat162float(pp1[idx]);
        float l2 = __bfloat162float(pp2[idx]);
        float l3 = __bfloat162float(pp3[idx]);
        float pre = bv + l0;
        pre = fmaf(m1, l1, pre);
        pre = fmaf(m2, l2, pre);
        pre = fmaf(m3, l3, pre);
        float th, s2;
        tanh_sech2_(pre, th, s2);
        const float* g0row = &g0s[bl * 68 + kb2];
        float dot = 0.f;
#pragma unroll
        for (int qq = 0; qq < 8; ++qq) {
            float4 gv = *(const float4*)&g0row[qq * 4];
            dot = fmaf(gv.x, er[qq].x, dot);
            dot = fmaf(gv.y, er[qq].y, dot);
            dot = fmaf(gv.z, er[qq].z, dot);
            dot = fmaf(gv.w, er[qq].w, dot);
        }
        bf16 thb = __float2bfloat16(th);
        h1s[bl * 68 + nl] = *(const short*)&thb;
        grad1e[idx] = __float2bfloat16(dot * s2);
    }
    __syncthreads();

    int rf = lane & 15;
    int q = lane >> 4;
    floatx4 acc2[4];
#pragma unroll
    for (int j = 0; j < 4; ++j) acc2[j] = (floatx4){0.f, 0.f, 0.f, 0.f};

#pragma unroll
    for (int s = 0; s < 2; ++s) {
        int rowa = wave * 16 + rf;
        short8 af = *(const short8*)&h1s[rowa * 68 + s * 32 + q * 8];
#pragma unroll
        for (int j = 0; j < 4; ++j) {
            int rowb = j * 16 + rf;
            int cp = (s * 4 + q) ^ (rowb & 7);
            short8 bfv = *(const short8*)&Bs2[rowb * 64 + cp * 8];
            acc2[j] = __builtin_amdgcn_mfma_f32_16x16x32_bf16(af, bfv, acc2[j], 0, 0, 0);
        }
    }

    float* outk = out2p + (size_t)bx * BATCH * DIMN;
    int col = lane & 15;
    int rq = (lane >> 4) * 4;
#pragma unroll
    for (int j = 0; j < 4; ++j) {
#pragma unroll
        for (int r = 0; r < 4; ++r) {
            int m = b0 + wave * 16 + rq + r;
            outk[(size_t)m * DIMN + j * 16 + col] = acc2[j][r];
        }
    }
}

// ---------------------------------------------------------------------------
// tail_trans (R27): 2 rows per 128-thread block, grid 512 (2 blocks/CU).
// ---------------------------------------------------------------------------
__global__ __launch_bounds__(128) void tail_trans(
    const float* __restrict__ out2p, const float* __restrict__ b2,
    const float* __restrict__ e2, const bf16* __restrict__ grad1e,
    const float* __restrict__ x_cur, const float* __restrict__ gate,
    float* __restrict__ x_next, float* __restrict__ ldj, int accum_ldj)
{
    int tid = threadIdx.x;
    int b = blockIdx.x * 2 + (tid >> 6);
    int n = tid & 63;

    float o = b2[n];
#pragma unroll
    for (int p = 0; p < NT2; ++p)
        o += out2p[(size_t)p * BATCH * DIMN + (size_t)b * DIMN + n];

    float gt = gate[0];
    float sg = 1.f / (1.f + __expf(-gt));
    float xo = sg * o + (1.f - sg) * x_cur[(size_t)b * DIMN + n];
    x_next[(size_t)b * DIMN + (63 - n)] = xo;

    const short8* gr = (const short8*)((const short*)grad1e + (size_t)b * HIDF + n * 32);
    const float4* gc = (const float4*)(e2 + n * 32);
    float s = 0.f;
#pragma unroll
    for (int q = 0; q < 4; ++q) {
        short8 a8 = gr[q];
        float4 c0 = gc[2 * q], c1 = gc[2 * q + 1];
        s = fmaf(bf2f(a8[0]), c0.x, s);
        s = fmaf(bf2f(a8[1]), c0.y, s);
        s = fmaf(bf2f(a8[2]), c0.z, s);
        s = fmaf(bf2f(a8[3]), c0.w, s);
        s = fmaf(bf2f(a8[4]), c1.x, s);
        s = fmaf(bf2f(a8[5]), c1.y, s);
        s = fmaf(bf2f(a8[6]), c1.z, s);
        s = fmaf(bf2f(a8[7]), c1.w, s);
    }
    float gF = __logf(fmaxf(s, 1e-45f));
    float contrib = softplusf_(gF + gt) - softplusf_(gt);
    for (int off = 32; off > 0; off >>= 1) contrib += __shfl_xor(contrib, off, 64);
    if (n == 0) ldj[b] = accum_ldj ? (ldj[b] + contrib) : contrib;
}

// ---------------------------------------------------------------------------
// tail_final (R27): 2 rows per 128-thread block, grid 512.
// ---------------------------------------------------------------------------
__global__ __launch_bounds__(128) void tail_final(
    const float* __restrict__ out2p, const float* __restrict__ b2,
    const float* __restrict__ e2, const bf16* __restrict__ grad1e,
    const float* __restrict__ ldj, float* __restrict__ out)
{
    int tid = threadIdx.x;
    int b = blockIdx.x * 2 + (tid >> 6);
    int n = tid & 63;

    float o = b2[n];
#pragma unroll
    for (int p = 0; p < NT2; ++p)
        o += out2p[(size_t)p * BATCH * DIMN + (size_t)b * DIMN + n];

    const short8* gr = (const short8*)((const short*)grad1e + (size_t)b * HIDF + n * 32);
    const float4* gc = (const float4*)(e2 + n * 32);
    float s = 0.f;
#pragma unroll
    for (int q = 0; q < 4; ++q) {
        short8 a8 = gr[q];
        float4 c0 = gc[2 * q], c1 = gc[2 * q + 1];
        s = fmaf(bf2f(a8[0]), c0.x, s);
        s = fmaf(bf2f(a8[1]), c0.y, s);
        s = fmaf(bf2f(a8[2]), c0.z, s);
        s = fmaf(bf2f(a8[3]), c0.w, s);
        s = fmaf(bf2f(a8[4]), c1.x, s);
        s = fmaf(bf2f(a8[5]), c1.y, s);
        s = fmaf(bf2f(a8[6]), c1.z, s);
        s = fmaf(bf2f(a8[7]), c1.w, s);
    }
    float gF = __logf(fmaxf(s, 1e-45f));

    float contrib = gF - 0.5f * o * o - 0.91893853320467274f;
    for (int off = 32; off > 0; off >>= 1) contrib += __shfl_xor(contrib, off, 64);
    if (n == 0) out[b] = ldj[b] + contrib;
}

// ---------------------------------------------------------------------------
extern "C" void kernel_launch(void* const* d_in, const int* in_sizes, int n_in,
                              void* d_out, int out_size, void* d_ws, size_t ws_size,
                              hipStream_t stream)
{
    (void)in_sizes; (void)n_in; (void)out_size; (void)ws_size;

    const float* x = (const float*)d_in[0];
    const float* gates[2] = { (const float*)d_in[28], (const float*)d_in[29] };

    char* ws = (char*)d_ws;
    size_t ofs = 0;
    auto alloc = [&](size_t bytes) { char* p = ws + ofs; ofs += (bytes + 255) & ~(size_t)255; return p; };

    bf16* wn1_all  = (bf16*)alloc((size_t)3 * HIDF * HIDF * 2);   // 24 MB
    bf16* wn2b_all = (bf16*)alloc((size_t)3 * DIMN * HIDF * 2);
    float* wn0T_all = (float*)alloc((size_t)3 * DIMN * HIDF * 4);
    float* eg0_all  = (float*)alloc((size_t)3 * HIDF * 4);
    float* e1_all   = (float*)alloc((size_t)3 * HIDF * 32 * 4);
    float* e2_all   = (float*)alloc((size_t)3 * DIMN * 32 * 4);
    bf16* h0   = (bf16*)alloc((size_t)BATCH * HIDF * 2);
    bf16* part = (bf16*)alloc((size_t)SPLITK * BATCH * HIDF * 2); // 16 MB
    bf16* g0e    = (bf16*)alloc((size_t)BATCH * HIDF * 2);
    bf16* grad1e = (bf16*)alloc((size_t)BATCH * HIDF * 2);
    float* out2p  = (float*)alloc((size_t)NT2 * BATCH * DIMN * 4); // 8 MB
    float* x1     = (float*)alloc((size_t)BATCH * DIMN * 4);
    float* x2     = (float*)alloc((size_t)BATCH * DIMN * 4);
    float* ldj    = (float*)alloc(BATCH * 4);
    float* outp   = (float*)d_out;

    auto W = [&](int f, int i) { return (const float*)d_in[1 + f * 9 + i]; };

    PrepIn p0 = { W(0,0), W(0,1), W(0,3), W(0,4), W(0,6), W(0,7) };
    PrepIn p1 = { W(1,0), W(1,1), W(1,3), W(1,4), W(1,6), W(1,7) };
    PrepIn p2 = { W(2,0), W(2,1), W(2,3), W(2,4), W(2,6), W(2,7) };

    prep_mega<<<dim3(3 * 1040), dim3(256), 0, stream>>>(
        p0, p1, p2, wn0T_all, eg0_all, wn1_all, e1_all, wn2b_all, e2_all);

    gemm0_act<<<dim3(8, BATCH / 16), dim3(256), 0, stream>>>(
        x, wn0T_all, W(0,2), eg0_all, h0, g0e);

    const float* xcur = x;
    float* xnexts[2] = { x1, x2 };

    for (int f = 0; f < 3; ++f) {
        size_t fo1 = (size_t)f * HIDF * HIDF;
        size_t fo2 = (size_t)f * DIMN * HIDF;

        gemm1_part<<<dim3(640), dim3(256), 0, stream>>>(
            h0, wn1_all + fo1, part);

        act_grad_gemm2<<<dim3(HIDF / 64, BATCH / 64), dim3(256), 0, stream>>>(
            part, W(f,5), e1_all + (size_t)f * HIDF * 32, g0e,
            wn2b_all + fo2, grad1e, out2p);

        if (f < 2) {
            tail_trans<<<dim3(BATCH / 2), dim3(128), 0, stream>>>(
                out2p, W(f,8), e2_all + (size_t)f * DIMN * 32, grad1e,
                xcur, gates[f], xnexts[f], ldj, f);

            gemm0_act<<<dim3(8, BATCH / 16), dim3(256), 0, stream>>>(
                xnexts[f], wn0T_all + (size_t)(f + 1) * DIMN * HIDF, W(f + 1, 2),
                eg0_all + (size_t)(f + 1) * HIDF, h0, g0e);

            xcur = xnexts[f];
        } else {
            tail_final<<<dim3(BATCH / 2), dim3(128), 0, stream>>>(
                out2p, W(2,8), e2_all + (size_t)2 * DIMN * 32, grad1e, ldj, outp);
        }
    }
}